// Round 1
// baseline (16496.434 us; speedup 1.0000x reference)
//
#include <hip/hip_runtime.h>
#include <math.h>

namespace {

constexpr int N_   = 200;   // nodes
constexpr int H_   = 20;    // inner steps
constexpr int B_   = 400;   // outer steps
constexpr int OUT_ = 64;    // eeg channels
constexpr int BUF_ = 500;   // hE buffer length
constexpr int NT_  = 1024;  // block size (16 waves, 1 CU persistent)
constexpr int DCAP = 1536;  // dynamic (delay==0) entry capacity (~800 expected)
constexpr int HD_  = 50;    // history depth (max delay = 49)
constexpr int HP_  = 201;   // padded history row stride (bank-conflict fix)

constexpr float DT_   = 0.0001f;
constexpr float VMAX_ = 5.0f;
constexpr float V0_   = 6.0f;
constexpr float R_    = 0.56f;
constexpr float UUB_  = 500.0f;
constexpr float G_    = 1000.01f;   // 0.01 + 1000
constexpr float C1_   = 135.01f;    // 0.01 + 135
constexpr float C2_   = 108.01f;    // 0.01 + 135*0.8
constexpr float C3_   = 33.76f;     // 0.01 + 135*0.25
constexpr float C4_   = 33.76f;
constexpr float STD_  = 250.0f;     // 150 + 100
constexpr float K_    = 5.5f;       // 0.5 + 5
constexpr float A_    = 3.25f;
constexpr float a_    = 101.0f;     // 1 + 100
constexpr float Bb_   = 22.0f;
constexpr float b_    = 51.0f;      // 1 + 50
constexpr float CY0_  = 5.0f;
constexpr float Y0_   = 2.0f;

__device__ __forceinline__ float sig_(float x) {
    return VMAX_ / (1.0f + expf(R_ * (V0_ - x)));
}
__device__ __forceinline__ float sat_(float x) {
    return 1000.0f * tanhf(x / 1000.0f);
}
// wl[i][j] = log1p(0.5*(exp(wbb[i,j])*sc[i,j] + exp(wbb[j,i])*sc[j,i]))
__device__ __forceinline__ float wl_ij(const float* __restrict__ wbb,
                                       const float* __restrict__ sc,
                                       int i, int j) {
    float w0 = expf(wbb[i * N_ + j]) * sc[i * N_ + j];
    float w1 = expf(wbb[j * N_ + i]) * sc[j * N_ + i];
    return log1pf(0.5f * (w0 + w1));
}

__global__ __launch_bounds__(NT_) void jansen_kernel(
    const float* __restrict__ input,     // (N,H,B)
    const float* __restrict__ noise_in,  // (N,H,B,3) — only [...,0] used
    const float* __restrict__ hx,        // (N,6)
    const float* __restrict__ hEin,      // (N,500)
    const float* __restrict__ wbb,       // (N,N)
    const float* __restrict__ lm,        // (64,N)
    const float* __restrict__ sc,        // (N,N)
    const int*   __restrict__ dist,      // (N,N) int32
    float* __restrict__ out)             // 64*400 eeg.T + N*6 state
{
    __shared__ float hist[HD_ * HP_];    // circular M_end history, hist[c*HP_+j]
    __shared__ float led_part[5 * N_];   // static-gather partials (5 slots/row)
    __shared__ float mcol[2 * N_];       // double-buffered hEb column 0
    __shared__ float rowsum_s[N_];       // sum_j w_n[i,j]  (for dg term)
    __shared__ float emi[N_];            // E - I (for eeg)
    __shared__ int   rowptr[N_ + 1];     // dynamic CSR
    __shared__ int   dynJ[DCAP];
    __shared__ float dynW[DCAP];
    __shared__ float colmean[N_];        // sum_o lm1[o,j] / OUT
    __shared__ float lmrs[OUT_];         // sum_j |lm[o,j]|
    __shared__ float red_s[NT_ / 64];
    __shared__ float norm_s;

    const int t = threadIdx.x;

    // ---- phase 1: Frobenius norm of wl ----
    float ss = 0.0f;
    for (int k = t; k < N_ * N_; k += NT_) {
        int i = k / N_, j = k - i * N_;
        float w = wl_ij(wbb, sc, i, j);
        ss += w * w;
    }
    #pragma unroll
    for (int o = 32; o > 0; o >>= 1) ss += __shfl_down(ss, o, 64);
    if ((t & 63) == 0) red_s[t >> 6] = ss;
    __syncthreads();
    if (t == 0) {
        float tot = 0.0f;
        for (int w = 0; w < NT_ / 64; ++w) tot += red_s[w];
        norm_s = sqrtf(tot);
    }
    __syncthreads();
    const float nrm = norm_s;

    // ---- phase 2: rowsum, dyn counts, lm row abs-sums ----
    if (t < N_) {
        float rs = 0.0f; int cnt = 0;
        for (int j = 0; j < N_; ++j) {
            rs += wl_ij(wbb, sc, t, j) / nrm;
            cnt += ((dist[j * N_ + t] >> 1) == 0) ? 1 : 0;   // delays[j][t]==0
        }
        rowsum_s[t] = rs;
        rowptr[t + 1] = cnt;
    }
    if (t < OUT_) {
        float rs = 0.0f;
        for (int j = 0; j < N_; ++j) rs += fabsf(lm[t * N_ + j]);
        lmrs[t] = rs;
    }
    if (t == 0) rowptr[0] = 0;
    __syncthreads();

    // ---- phase 3: serial prefix sum (setup-only, 200 iters) ----
    if (t == 0) {
        for (int i = 1; i <= N_; ++i) rowptr[i] += rowptr[i - 1];
    }
    __syncthreads();

    // ---- phase 4: CSR fill, colmean, hist zero, per-thread register fill ----
    if (t < N_) {
        int p = rowptr[t];
        for (int j = 0; j < N_; ++j) {
            if ((dist[j * N_ + t] >> 1) == 0) {
                if (p < DCAP) { dynJ[p] = j; dynW[p] = wl_ij(wbb, sc, t, j) / nrm; }
                ++p;
            }
        }
        float cm = 0.0f;
        for (int o = 0; o < OUT_; ++o) cm += lm[o * N_ + t] / lmrs[o];
        colmean[t] = cm / (float)OUT_;
    }
    for (int k = t; k < HD_ * HP_; k += NT_) hist[k] = 0.0f;

    // static-gather entries: thread t<1000 owns row=t/5, j in [slot*40, slot*40+40)
    float wreg[40];
    unsigned meta[20];   // two packed (j | d<<8) entries per int
    const int grow  = t / 5;
    const int gslot = t - grow * 5;
    if (t < 1000) {
        #pragma unroll
        for (int m = 0; m < 40; ++m) {
            int j = gslot * 40 + m;
            int d = dist[j * N_ + grow] >> 1;          // delays[j][grow]
            float w = (d == 0) ? 0.0f : (wl_ij(wbb, sc, grow, j) / nrm);
            wreg[m] = w;
            unsigned ent = (unsigned)j | ((unsigned)d << 8);
            if ((m & 1) == 0) meta[m >> 1] = ent;
            else              meta[m >> 1] |= (ent << 16);
        }
    } else {
        #pragma unroll
        for (int m = 0; m < 40; ++m) wreg[m] = 0.0f;
        #pragma unroll
        for (int m = 0; m < 20; ++m) meta[m] = 0u;
    }
    __syncthreads();

    // ---- phase 5: hist overlay from hE, mcol + per-node state init ----
    float M = 0, E = 0, I = 0, Mv = 0, Ev = 0, Iv = 0;
    float rsum = 0, u_cur = 0, ne_cur = 0;
    int p0r = 0, p1r = 0, ubase = 0;
    if (t < N_) {
        // initial hEb col k (k=1..49) lives at slot (0-k) mod 50 = 50-k
        for (int k = 1; k < HD_; ++k) hist[(HD_ - k) * HP_ + t] = hEin[t * BUF_ + k];
        mcol[t] = hEin[t * BUF_ + 0];  // first-ever col-0 read is hE[:,0], not M!
        M  = hx[t * 6 + 0]; E  = hx[t * 6 + 1]; I  = hx[t * 6 + 2];
        Mv = hx[t * 6 + 3]; Ev = hx[t * 6 + 4]; Iv = hx[t * 6 + 5];
        rsum = rowsum_s[t];
        p0r = rowptr[t]; p1r = rowptr[t + 1];
        ubase = t * (H_ * B_);
        u_cur  = input[ubase];            // (i, h=0, b=0)
        ne_cur = noise_in[ubase * 3];     // (i, 0, 0, 0)
    }
    __syncthreads();

    // ---- main sequential loop: 400 outer x 20 inner ----
    int pr = 0;
    int smod = 0;                          // s % 50
    for (int s = 0; s < B_; ++s) {
        // static delayed gather (delays>=1): constant across the 20 inner steps
        if (t < 1000) {
            float acc = 0.0f;
            #pragma unroll
            for (int m = 0; m < 20; ++m) {
                unsigned mm = meta[m];
                int j0 = (int)(mm & 255u);
                int d0 = (int)((mm >> 8) & 63u);
                int j1 = (int)((mm >> 16) & 255u);
                int d1 = (int)((mm >> 24) & 63u);
                int c0 = smod - d0; if (c0 < 0) c0 += HD_;
                int c1 = smod - d1; if (c1 < 0) c1 += HD_;
                acc += wreg[2 * m]     * hist[c0 * HP_ + j0];
                acc += wreg[2 * m + 1] * hist[c1 * HP_ + j1];
            }
            led_part[gslot * N_ + grow] = acc;
        }
        __syncthreads();
        float ledst = 0.0f;
        if (t < N_) {
            ledst = led_part[t] + led_part[N_ + t] + led_part[2 * N_ + t]
                  + led_part[3 * N_ + t] + led_part[4 * N_ + t];
        }
        for (int h = 0; h < H_; ++h) {
            if (t < N_) {
                float LEd = ledst;
                const float* mc = &mcol[pr * N_];
                for (int p = p0r; p < p1r; ++p) LEd += dynW[p] * mc[dynJ[p]];

                float u = u_cur, ne = ne_cur;
                // prefetch next step's u / noise
                int hn = h + 1, sn = s;
                if (hn == H_) { hn = 0; sn = (s + 1 < B_) ? (s + 1) : s; }
                int idx = ubase + hn * B_ + sn;
                u_cur  = input[idx];
                ne_cur = noise_in[idx * 3];

                float rM = sig_(E - I);
                float rE = STD_ * ne + G_ * (LEd - rsum * E) + C2_ * sig_(C1_ * M);
                float rI = C4_ * sig_(C3_ * M);
                float ddM = M + DT_ * Mv;
                float ddE = E + DT_ * Ev;
                float ddI = I + DT_ * Iv;
                float uM = UUB_ * tanhf(rM / UUB_);
                float uE = K_ * u + UUB_ * tanhf(rE / UUB_);
                float uI = UUB_ * tanhf(rI / UUB_);
                float ddMv = Mv + DT_ * (A_ * a_ * uM - 2.0f * a_ * Mv - a_ * a_ * M);
                float ddEv = Ev + DT_ * (A_ * a_ * uE - 2.0f * a_ * Ev - a_ * a_ * E);
                float ddIv = Iv + DT_ * (Bb_ * b_ * uI - 2.0f * b_ * Iv - b_ * b_ * I);
                M  = sat_(ddM);  E  = sat_(ddE);  I  = sat_(ddI);
                Mv = sat_(ddMv); Ev = sat_(ddEv); Iv = sat_(ddIv);
                mcol[(pr ^ 1) * N_ + t] = M;     // hEb[:,0] = new M
            }
            __syncthreads();
            pr ^= 1;
        }
        // outer boundary: history shift (circular write) + eeg
        if (t < N_) {
            hist[smod * HP_ + t] = M;            // M_end(s) at slot s%50
            emi[t] = E - I;
        }
        __syncthreads();
        {   // eeg[o] = CY0 * sum_j (lm[o,j]/lmrs[o] - colmean[j]) * emi[j] - Y0
            int o = t >> 4, l = t & 15;          // 16 lanes per output row
            float acc = 0.0f;
            for (int j = l; j < N_; j += 16)
                acc += (lm[o * N_ + j] / lmrs[o] - colmean[j]) * emi[j];
            acc += __shfl_down(acc, 8, 16);
            acc += __shfl_down(acc, 4, 16);
            acc += __shfl_down(acc, 2, 16);
            acc += __shfl_down(acc, 1, 16);
            if (l == 0) out[o * B_ + s] = CY0_ * acc - Y0_;
        }
        ++smod; if (smod == HD_) smod = 0;
    }

    // final state: (N,6) concat [M,E,I,Mv,Ev,Iv]
    if (t < N_) {
        float* cs = out + OUT_ * B_ + t * 6;
        cs[0] = M; cs[1] = E; cs[2] = I; cs[3] = Mv; cs[4] = Ev; cs[5] = Iv;
    }
}

} // namespace

extern "C" void kernel_launch(void* const* d_in, const int* in_sizes, int n_in,
                              void* d_out, int out_size, void* d_ws, size_t ws_size,
                              hipStream_t stream)
{
    const float* input    = (const float*)d_in[0];
    const float* noise_in = (const float*)d_in[1];
    // d_in[2] = noise_out (unused by the reference forward pass)
    const float* hx   = (const float*)d_in[3];
    const float* hEin = (const float*)d_in[4];
    const float* wbb  = (const float*)d_in[5];
    const float* lm   = (const float*)d_in[6];
    const float* sc   = (const float*)d_in[7];
    const int*   dist = (const int*)d_in[8];
    float* out = (float*)d_out;

    hipLaunchKernelGGL(jansen_kernel, dim3(1), dim3(NT_), 0, stream,
                       input, noise_in, hx, hEin, wbb, lm, sc, dist, out);
}

// Round 2
// 13144.519 us; speedup vs baseline: 1.2550x; 1.2550x over previous
//
#include <hip/hip_runtime.h>
#include <math.h>

namespace {

constexpr int N_   = 200;   // nodes
constexpr int H_   = 20;    // inner steps
constexpr int B_   = 400;   // outer steps
constexpr int OUT_ = 64;    // eeg channels
constexpr int BUF_ = 500;   // hE buffer length
constexpr int NT_  = 1024;  // 16 waves, single persistent workgroup
constexpr int HD_  = 50;    // history depth (max delay 49)
constexpr int HP_  = 201;   // padded history stride (odd -> bank spread)
constexpr int DC_  = 16;    // per-row dynamic-CSR capacity (Binom(200,.02) max ~12)
constexpr int DP_  = 17;    // padded CSR stride

constexpr float L2E = 1.4426950408889634f;
constexpr float LN2 = 0.6931471805599453f;

constexpr float DT_  = 0.0001f;
constexpr float G_   = 1000.01f;    // 0.01 + 1000
constexpr float C1_  = 135.01f;
constexpr float C2_  = 108.01f;
constexpr float C3_  = 33.76f;
constexpr float C4_  = 33.76f;
constexpr float STD_ = 250.0f;
constexpr float K_   = 5.5f;
constexpr float CY0_ = 5.0f;
constexpr float Y0_  = 2.0f;

constexpr float RL2E = 0.56f * L2E;           // R*log2e
constexpr float V0R  = 6.0f * RL2E;           // V0*R*log2e
constexpr float TU_  = 2.0f * L2E / 500.0f;   // 500*tanh(x/500) exponent scale
constexpr float TS_  = 2.0f * L2E / 1000.0f;  // sat exponent scale

// ddXv = Xv + DT*(A*a*u - 2a*Xv - a^2*X) = KXv*Xv + KXu*u - KXx*X
constexpr float KMv = 0.9798f, KMu = 0.0328250f, KMx = 1.0201f;
constexpr float KEv = 0.9798f, KEu = 0.0328250f, KEx = 1.0201f;
constexpr float KIv = 0.9898f, KIu = 0.1122000f, KIx = 0.2601f;

__device__ __forceinline__ float fexp2(float x){ return __builtin_amdgcn_exp2f(x); }
__device__ __forceinline__ float flog2(float x){ return __builtin_amdgcn_logf(x); }
__device__ __forceinline__ float frcp (float x){ return __builtin_amdgcn_rcpf(x); }

__device__ __forceinline__ float sigf(float x){        // VMAX/(1+exp(R*(V0-x)))
    return 5.0f * frcp(1.0f + fexp2(fmaf(-RL2E, x, V0R)));
}
__device__ __forceinline__ float tanh500(float x){     // 500*tanh(x/500), overflow-safe
    return 500.0f - 1000.0f * frcp(1.0f + fexp2(x * TU_));
}
__device__ __forceinline__ float satf(float x){        // 1000*tanh(x/1000)
    return 1000.0f - 2000.0f * frcp(1.0f + fexp2(x * TS_));
}
// wl[i][j] = log1p(0.5*(exp(wbb[i,j])*sc[i,j] + exp(wbb[j,i])*sc[j,i]))
__device__ __forceinline__ float wl_f(const float* __restrict__ wbb,
                                      const float* __restrict__ sc,
                                      int i, int j){
    float w0 = fexp2(wbb[i*N_+j]*L2E) * sc[i*N_+j];
    float w1 = fexp2(wbb[j*N_+i]*L2E) * sc[j*N_+i];
    return flog2(1.0f + 0.5f*(w0+w1)) * LN2;
}

__global__ __launch_bounds__(NT_) void jansen_kernel(
    const float* __restrict__ input,     // (N,H,B)
    const float* __restrict__ noise_in,  // (N,H,B,3) — only [...,0] used
    const float* __restrict__ hx,        // (N,6)
    const float* __restrict__ hEin,      // (N,500)
    const float* __restrict__ wbb,       // (N,N)
    const float* __restrict__ lm,        // (64,N)
    const float* __restrict__ sc,        // (N,N)
    const int*   __restrict__ dist,      // (N,N)
    float* __restrict__ out)             // 64*400 eeg + N*6 state
{
    __shared__ float  hist[HD_*HP_];     // circular M_end history
    __shared__ float  led_part[5*N_];    // gather partials (5 slots/row)
    __shared__ float  mcol[2*N_];        // double-buffered hEb column 0
    __shared__ float  emi[N_];           // E-I at boundary
    __shared__ float  colmean[N_];
    __shared__ float  lmrs[OUT_];
    __shared__ float2 dyn0P[N_*DP_];     // delay==0 CSR: {w, bitcast(j)}
    __shared__ float2 dyn1P[N_*DP_];     // delay==1 CSR
    __shared__ float  red_s[NT_/64];
    __shared__ float  norm_s;

    const int t = threadIdx.x;
    const int grow  = t / 5;             // gather row (t<1000)
    const int gslot = t - grow*5;        // gather slot 0..4
    const bool isg = (t < 1000);
    const bool isr = (t < N_);

    float wreg[40];                      // static-gather weights (d>=2, normalized)
    unsigned meta[20];                   // packed (j | d<<8) x2 per u32

    // ---- phase A: wl for own 40 entries; Frobenius partial + rowsum partial ----
    float ss = 0.f, rs = 0.f;
    #pragma unroll
    for (int m=0;m<40;++m){
        int j = gslot*40+m;
        float w = 0.f; int d = 2;
        if (isg){
            d = dist[j*N_+grow] >> 1;    // delays[j][grow]
            w = wl_f(wbb, sc, grow, j);
        }
        ss = fmaf(w,w,ss); rs += w;
        wreg[m] = (d>=2) ? w : 0.f;      // d<2 handled by CSRs; weight zeroed here
        int dm = (d<2) ? 2 : d;          // clamp so reads stay on valid slots
        unsigned ent = (unsigned)j | ((unsigned)dm<<8);
        if ((m&1)==0) meta[m>>1] = ent; else meta[m>>1] |= (ent<<16);
    }
    if (t < OUT_){
        float s2=0.f;
        for (int j=0;j<N_;++j) s2 += fabsf(lm[t*N_+j]);
        lmrs[t] = s2;
    }
    #pragma unroll
    for (int o=32;o>0;o>>=1) ss += __shfl_down(ss,o,64);
    if ((t&63)==0) red_s[t>>6] = ss;
    __syncthreads();
    if (t==0){ float tot=0.f; for(int w=0;w<NT_/64;++w) tot+=red_s[w]; norm_s = sqrtf(tot); }
    __syncthreads();
    const float inv = 1.0f / norm_s;
    #pragma unroll
    for (int m=0;m<40;++m) wreg[m] *= inv;
    if (isg) led_part[gslot*N_+grow] = rs;
    __syncthreads();

    // ---- phase B: row threads — rowsum, CSRs, hist overlay, state ----
    float M=0,E=0,I=0,Mv=0,Ev=0,Iv=0, rowsum=0, ledst=0, u_cur=0, ne_cur=0;
    int cnt0=0, cnt1=0, ubase=0;
    if (isr){
        rowsum = (led_part[t]+led_part[N_+t]+led_part[2*N_+t]
                 +led_part[3*N_+t]+led_part[4*N_+t]) * inv;
        for (int j=0;j<N_;++j){
            int dd = dist[j*N_+t] >> 1;
            if (dd < 2){
                float2 p; p.x = wl_f(wbb, sc, t, j) * inv; p.y = __int_as_float(j);
                if (dd==0){ if (cnt0<DC_) dyn0P[t*DP_+cnt0++] = p; }
                else      { if (cnt1<DC_) dyn1P[t*DP_+cnt1++] = p; }
            }
        }
        // initial hEb col k (k=1..49) -> slot (0-k) mod 50 = 50-k
        for (int k=1;k<HD_;++k) hist[(HD_-k)*HP_+t] = hEin[t*BUF_+k];
        mcol[t] = hEin[t*BUF_];          // first col-0 read is hE[:,0]
        M=hx[t*6+0]; E=hx[t*6+1]; I=hx[t*6+2]; Mv=hx[t*6+3]; Ev=hx[t*6+4]; Iv=hx[t*6+5];
        float cm=0.f;
        for (int o=0;o<OUT_;++o) cm += lm[o*N_+t] * frcp(lmrs[o]);
        colmean[t] = cm * (1.0f/(float)OUT_);
        ubase = t*(H_*B_);
        u_cur  = input[ubase];
        ne_cur = noise_in[ubase*3];
    }
    __syncthreads();

    // ---- phase C: full static gather for s=0 (smod1=0 -> slot 50-d) ----
    {
        float acc0 = 0.f;
        if (isg){
            #pragma unroll
            for (int m=0;m<20;++m){
                unsigned mm = meta[m];
                int j0=mm&255, d0=(mm>>8)&63, j1=(mm>>16)&255, d1=(mm>>24)&63;
                acc0 = fmaf(wreg[2*m],   hist[(HD_-d0)*HP_+j0], acc0);
                acc0 = fmaf(wreg[2*m+1], hist[(HD_-d1)*HP_+j1], acc0);
            }
            led_part[gslot*N_+grow] = acc0;
        }
    }
    __syncthreads();
    if (isr){
        float v = led_part[t]+led_part[N_+t]+led_part[2*N_+t]
                 +led_part[3*N_+t]+led_part[4*N_+t];
        for (int k=0;k<cnt1;++k){        // d==1 at s=0 reads init col 1 = slot 49
            float2 p = dyn1P[t*DP_+k];
            v = fmaf(p.x, hist[49*HP_+__float_as_int(p.y)], v);
        }
        ledst = v;
    }
    __syncthreads();

    // ---- main loop: 400 outer x 20 inner; gather for s+1 overlapped ----
    int smod = 0;                        // s % 50
    for (int s=0; s<B_; ++s){
        int smod1 = smod+1; if (smod1==HD_) smod1 = 0;   // (s+1) % 50
        float acc = 0.f;
        #pragma unroll
        for (int h=0; h<H_; ++h){
            // 2-entry gather chunk for outer step s+1 (d>=2 only -> no hazard
            // with this step's boundary write; slots written at <= s-1)
            float g0=0.f, g1=0.f, w0=0.f, w1=0.f;
            if (isg){
                unsigned mm = meta[h];
                int j0=mm&255, d0=(mm>>8)&63, j1=(mm>>16)&255, d1=(mm>>24)&63;
                int c0 = smod1-d0; if (c0<0) c0 += HD_;
                int c1 = smod1-d1; if (c1<0) c1 += HD_;
                g0 = hist[c0*HP_+j0]; g1 = hist[c1*HP_+j1];
                w0 = wreg[2*h]; w1 = wreg[2*h+1];
            }
            if (isr){
                const float* mc = &mcol[(h&1)*N_];
                float LEd = ledst;
                for (int k=0;k<cnt0;++k){
                    float2 p = dyn0P[t*DP_+k];
                    LEd = fmaf(p.x, mc[__float_as_int(p.y)], LEd);
                }
                float u = u_cur, ne = ne_cur;
                int sn = (h==H_-1) ? ((s+1<B_)? s+1 : s) : s;
                int hn = (h==H_-1) ? 0 : h+1;
                int idx = ubase + hn*B_ + sn;
                u_cur  = input[idx];             // prefetch next step
                ne_cur = noise_in[idx*3];

                float rM = sigf(E - I);
                float rE = fmaf(STD_, ne, G_*(LEd - rowsum*E)) + C2_*sigf(C1_*M);
                float rI = C4_*sigf(C3_*M);
                float uM = tanh500(rM);
                float uE = fmaf(K_, u, tanh500(rE));
                float uI = tanh500(rI);
                float ddM = fmaf(DT_, Mv, M);
                float ddE = fmaf(DT_, Ev, E);
                float ddI = fmaf(DT_, Iv, I);
                float ddMv = fmaf(KMv, Mv, fmaf(KMu, uM, -KMx*M));
                float ddEv = fmaf(KEv, Ev, fmaf(KEu, uE, -KEx*E));
                float ddIv = fmaf(KIv, Iv, fmaf(KIu, uI, -KIx*I));
                M  = satf(ddM);  E  = satf(ddE);  I  = satf(ddI);
                Mv = satf(ddMv); Ev = satf(ddEv); Iv = satf(ddIv);
                mcol[((h&1)^1)*N_+t] = M;        // hEb[:,0] = new M
            }
            acc = fmaf(w0, g0, acc);
            acc = fmaf(w1, g1, acc);
            __syncthreads();
        }
        // ---- outer boundary ----
        if (isr){ hist[smod*HP_+t] = M; emi[t] = E - I; }
        if (isg)  led_part[gslot*N_+grow] = acc;
        __syncthreads();
        if (isr){
            float v = led_part[t]+led_part[N_+t]+led_part[2*N_+t]
                     +led_part[3*N_+t]+led_part[4*N_+t];
            const float* mc = &mcol[0];          // = M_end(s): d==1 term for s+1
            for (int k=0;k<cnt1;++k){
                float2 p = dyn1P[t*DP_+k];
                v = fmaf(p.x, mc[__float_as_int(p.y)], v);
            }
            ledst = v;
        }
        {   // eeg[o] = CY0 * sum_j (lm[o,j]/lmrs[o] - colmean[j]) * emi[j] - Y0
            int o = t>>4, l = t&15;
            float il = frcp(lmrs[o]);
            float a2 = 0.f;
            for (int j=l;j<N_;j+=16)
                a2 = fmaf(fmaf(lm[o*N_+j], il, -colmean[j]), emi[j], a2);
            a2 += __shfl_down(a2,8,16); a2 += __shfl_down(a2,4,16);
            a2 += __shfl_down(a2,2,16); a2 += __shfl_down(a2,1,16);
            if (l==0) out[o*B_+s] = fmaf(CY0_, a2, -Y0_);
        }
        smod = smod1;
    }

    // ---- final state (N,6): [M,E,I,Mv,Ev,Iv] ----
    if (isr){
        float* cs = out + OUT_*B_ + t*6;
        cs[0]=M; cs[1]=E; cs[2]=I; cs[3]=Mv; cs[4]=Ev; cs[5]=Iv;
    }
}

} // namespace

extern "C" void kernel_launch(void* const* d_in, const int* in_sizes, int n_in,
                              void* d_out, int out_size, void* d_ws, size_t ws_size,
                              hipStream_t stream)
{
    const float* input    = (const float*)d_in[0];
    const float* noise_in = (const float*)d_in[1];
    // d_in[2] = noise_out (unused in forward)
    const float* hx   = (const float*)d_in[3];
    const float* hEin = (const float*)d_in[4];
    const float* wbb  = (const float*)d_in[5];
    const float* lm   = (const float*)d_in[6];
    const float* sc   = (const float*)d_in[7];
    const int*   dist = (const int*)d_in[8];
    float* out = (float*)d_out;

    hipLaunchKernelGGL(jansen_kernel, dim3(1), dim3(NT_), 0, stream,
                       input, noise_in, hx, hEin, wbb, lm, sc, dist, out);
}

// Round 3
// 10390.276 us; speedup vs baseline: 1.5877x; 1.2651x over previous
//
#include <hip/hip_runtime.h>
#include <math.h>

namespace {

constexpr int N_   = 200;   // nodes
constexpr int H_   = 20;    // inner steps
constexpr int B_   = 400;   // outer steps
constexpr int OUT_ = 64;    // eeg channels
constexpr int BUF_ = 500;   // hE buffer length
constexpr int NT_  = 1024;  // 16 waves, single persistent workgroup
constexpr int HD_  = 50;    // history depth (max delay 49)
constexpr int HP_  = 201;   // padded history stride
constexpr int GT0  = 224;   // first gather thread
constexpr int NG_  = 800;   // gather threads (4 per row)
constexpr int EPT  = 50;    // entries per gather thread
constexpr int CAP  = 24;    // CSR capacity (d==0 / d==1), Binom(200,.02) max ~13
constexpr int UNR  = 12;    // unrolled CSR entries (tail loop covers the rest)

constexpr float L2E = 1.4426950408889634f;
constexpr float LN2 = 0.6931471805599453f;

constexpr float DT_  = 0.0001f;
constexpr float G_   = 1000.01f;
constexpr float C1_  = 135.01f;
constexpr float C2_  = 108.01f;
constexpr float C3_  = 33.76f;
constexpr float C4_  = 33.76f;
constexpr float STD_ = 250.0f;
constexpr float K_   = 5.5f;
constexpr float CY0_ = 5.0f;
constexpr float Y0_  = 2.0f;

constexpr float RL2E = 0.56f * L2E;
constexpr float V0R  = 6.0f * RL2E;
constexpr float TU_  = 2.0f * L2E / 500.0f;
constexpr float TS_  = 2.0f * L2E / 1000.0f;

// ddXv = Xv + DT*(A*a*u - 2a*Xv - a^2*X)
constexpr float KMv = 0.9798f, KMu = 0.0328250f, KMx = 1.0201f;
constexpr float KEv = 0.9798f, KEu = 0.0328250f, KEx = 1.0201f;
constexpr float KIv = 0.9898f, KIu = 0.1122000f, KIx = 0.2601f;

__device__ __forceinline__ float fexp2(float x){ return __builtin_amdgcn_exp2f(x); }
__device__ __forceinline__ float flog2(float x){ return __builtin_amdgcn_logf(x); }
__device__ __forceinline__ float frcp (float x){ return __builtin_amdgcn_rcpf(x); }

__device__ __forceinline__ float sigf(float x){
    return 5.0f * frcp(1.0f + fexp2(fmaf(-RL2E, x, V0R)));
}
__device__ __forceinline__ float tanh500(float x){
    return 500.0f - 1000.0f * frcp(1.0f + fexp2(x * TU_));
}
__device__ __forceinline__ float satf(float x){
    return 1000.0f - 2000.0f * frcp(1.0f + fexp2(x * TS_));
}
__device__ __forceinline__ float wl_f(const float* __restrict__ wbb,
                                      const float* __restrict__ sc,
                                      int i, int j){
    float w0 = fexp2(wbb[i*N_+j]*L2E) * sc[i*N_+j];
    float w1 = fexp2(wbb[j*N_+i]*L2E) * sc[j*N_+i];
    return flog2(1.0f + 0.5f*(w0+w1)) * LN2;
}

__global__ __launch_bounds__(NT_) void jansen_kernel(
    const float* __restrict__ input,     // (N,H,B)
    const float* __restrict__ noise_in,  // (N,H,B,3)
    const float* __restrict__ hx,        // (N,6)
    const float* __restrict__ hEin,      // (N,500)
    const float* __restrict__ wbb,       // (N,N)
    const float* __restrict__ lm,        // (64,N)
    const float* __restrict__ sc,        // (N,N)
    const int*   __restrict__ dist,      // (N,N)
    float* __restrict__ out)             // 64*400 eeg + N*6 state
{
    __shared__ float hist[HD_*HP_];          // circular M_end history
    __shared__ float uslab[H_*N_];           // u for current outer step
    __shared__ float neslab[H_*N_];          // noise for current outer step
    __shared__ float d0w_l[CAP*N_];          // d==0 CSR weights (SoA)
    __shared__ unsigned char d0j_l[CAP*N_];  // d==0 CSR j (u8)
    __shared__ float d1w_l[CAP*N_];          // d==1 CSR weights
    __shared__ unsigned char d1j_l[CAP*N_];  // d==1 CSR j
    __shared__ float led_part[4*N_];         // static-gather partials
    __shared__ float mcol[2*N_];             // double-buffered hEb col 0
    __shared__ float emi[N_];
    __shared__ float colmean[N_];
    __shared__ float lmrs[OUT_];
    __shared__ float red_s[NT_/64];
    __shared__ float norm_s;

    const int t = threadIdx.x;
    const bool isr = (t < N_);
    const bool isg = (t >= GT0);             // 800 gather threads
    const int  gt  = t - GT0;                // 0..799
    const int  grow  = gt >> 2;              // row 0..199
    const int  gslot = gt & 3;               // slot 0..3

    float wreg[EPT];                         // static weights (normalized)
    unsigned meta[EPT/2];                    // packed (j | d<<8) x2

    // ===== S0: lmrs + state/hist/mcol init + initial slab (b=0) =====
    if (t < OUT_){
        float s2 = 0.f;
        for (int j=0;j<N_;++j) s2 += fabsf(lm[t*N_+j]);
        lmrs[t] = s2;
    }
    float M=0,E=0,I=0,Mv=0,Ev=0,Iv=0, rowsum=0, ledst=0;
    int cnt0=0, cnt1=0;
    if (isr){
        for (int k=1;k<HD_;++k) hist[(HD_-k)*HP_+t] = hEin[t*BUF_+k];
        mcol[t] = hEin[t*BUF_];
        M=hx[t*6+0]; E=hx[t*6+1]; I=hx[t*6+2];
        Mv=hx[t*6+3]; Ev=hx[t*6+4]; Iv=hx[t*6+5];
    }
    if (isg){
        #pragma unroll
        for (int r=0;r<5;++r){
            int p = r*NG_ + gt;
            int hh = p / N_, ii = p - hh*N_;
            uslab[hh*N_+ii]  = input[ii*(H_*B_) + hh*B_];
            neslab[hh*N_+ii] = noise_in[(ii*(H_*B_) + hh*B_)*3];
        }
    }
    __syncthreads();

    // ===== S1: gather wl entries, Frobenius + rowsum partials =====
    float ss = 0.f, rs = 0.f;
    #pragma unroll
    for (int m=0;m<EPT;++m){
        float w = 0.f; int d = 2;
        int j = gslot*EPT + m;
        if (isg){
            d = dist[j*N_+grow] >> 1;        // delays[j][grow]
            w = wl_f(wbb, sc, grow, j);
        }
        ss = fmaf(w,w,ss); rs += w;
        wreg[m] = (d>=2) ? w : 0.f;
        int dm = (d<2) ? 2 : d;
        unsigned ent = (unsigned)j | ((unsigned)dm<<8);
        if ((m&1)==0) meta[m>>1] = ent; else meta[m>>1] |= (ent<<16);
    }
    if (isr){                                 // colmean (needs lmrs)
        float cm=0.f;
        for (int o=0;o<OUT_;++o) cm += lm[o*N_+t] * frcp(lmrs[o]);
        colmean[t] = cm * (1.0f/(float)OUT_);
    }
    #pragma unroll
    for (int o=32;o>0;o>>=1) ss += __shfl_down(ss,o,64);
    if ((t&63)==0) red_s[t>>6] = ss;
    __syncthreads();
    if (t==0){ float tot=0.f; for (int w=0;w<NT_/64;++w) tot+=red_s[w]; norm_s = sqrtf(tot); }
    __syncthreads();
    const float inv = 1.0f / norm_s;
    #pragma unroll
    for (int m=0;m<EPT;++m) wreg[m] *= inv;
    if (isg) led_part[gslot*N_+grow] = rs;    // raw rowsum partial

    // ===== S3: row CSR build (d<2), registers for d0 =====
    float dw[UNR]; unsigned jpk[3];
    #pragma unroll
    for (int k=0;k<UNR;++k) dw[k] = 0.f;
    jpk[0]=jpk[1]=jpk[2]=0u;
    if (isr){
        #pragma unroll
        for (int k=0;k<UNR;++k){ d0w_l[k*N_+t]=0.f; d0j_l[k*N_+t]=0;
                                 d1w_l[k*N_+t]=0.f; d1j_l[k*N_+t]=0; }
        for (int j=0;j<N_;++j){
            int dd = dist[j*N_+t] >> 1;
            if (dd < 2){
                float w = wl_f(wbb, sc, t, j) * inv;
                if (dd==0){ if (cnt0<CAP){ d0w_l[cnt0*N_+t]=w; d0j_l[cnt0*N_+t]=(unsigned char)j; ++cnt0; } }
                else      { if (cnt1<CAP){ d1w_l[cnt1*N_+t]=w; d1j_l[cnt1*N_+t]=(unsigned char)j; ++cnt1; } }
            }
        }
        #pragma unroll
        for (int k=0;k<UNR;++k){
            dw[k] = d0w_l[k*N_+t];
            unsigned jv = d0j_l[k*N_+t];
            jpk[k>>2] |= jv << ((k&3)*8);
        }
    }
    __syncthreads();

    // ===== S4: rowsum =====
    if (isr){
        rowsum = (led_part[t]+led_part[N_+t]+led_part[2*N_+t]+led_part[3*N_+t]) * inv;
    }
    __syncthreads();

    // ===== S5: initial static gather for s=0 (target step 0 -> c = 50-d) =====
    if (isg){
        float a0 = 0.f;
        #pragma unroll
        for (int m=0;m<EPT;++m){
            unsigned mm = meta[m>>1];
            int j,d;
            if (m&1){ j=(mm>>16)&255; d=(mm>>24)&255; }
            else    { j=mm&255;       d=(mm>>8)&255; }
            int c = HD_ - d;                 // d in [2,49] -> c in [1,48]
            a0 = fmaf(wreg[m], hist[c*HP_+j], a0);
        }
        led_part[gslot*N_+grow] = a0;
    }
    __syncthreads();

    // ===== S6: initial ledst (+ d==1 from hE col 1 = slot 49) =====
    if (isr){
        float v = led_part[t]+led_part[N_+t]+led_part[2*N_+t]+led_part[3*N_+t];
        #pragma unroll
        for (int k=0;k<UNR;++k)
            v = fmaf(d1w_l[k*N_+t], hist[49*HP_ + d1j_l[k*N_+t]], v);
        for (int k=UNR;k<cnt1;++k)
            v = fmaf(d1w_l[k*N_+t], hist[49*HP_ + d1j_l[k*N_+t]], v);
        ledst = v;
    }
    __syncthreads();

    // ===== main loop =====
    int smod = 0;
    for (int s=0; s<B_; ++s){
        int ts = smod+1; if (ts==HD_) ts = 0;      // (s+1) % 50
        float acc = 0.f;
        #pragma unroll
        for (int h=0; h<H_; ++h){
            // --- gather chunk for outer step s+1 (entries 5q+2r, 2 or 3) ---
            if (isg){
                const int eb = 5*(h>>1) + 2*(h&1);
                const int ec = (h&1) ? 3 : 2;
                #pragma unroll
                for (int k=0;k<3;++k){
                    if (k < ec){
                        const int m = eb + k;
                        unsigned mm = meta[m>>1];
                        int j,d;
                        if (m&1){ j=(mm>>16)&255; d=(mm>>24)&255; }
                        else    { j=mm&255;       d=(mm>>8)&255; }
                        int c = ts - d; if (c<0) c += HD_;
                        acc = fmaf(wreg[m], hist[c*HP_+j], acc);
                    }
                }
            }
            if (isr){
                // --- M-path first: unblock next step ASAP ---
                float rM  = sigf(E - I);
                float uM  = tanh500(rM);
                float Mn  = satf(fmaf(DT_, Mv, M));
                float Mvn = satf(fmaf(KMv, Mv, fmaf(KMu, uM, -KMx*M)));
                mcol[((h&1)^1)*N_ + t] = Mn;
                // --- I-path (independent of LEd) ---
                float rI  = C4_*sigf(C3_*M);
                float uI  = tanh500(rI);
                float In  = satf(fmaf(DT_, Iv, I));
                float Ivn = satf(fmaf(KIv, Iv, fmaf(KIu, uI, -KIx*I)));
                // --- E-path ---
                float u  = uslab[h*N_+t];
                float ne = neslab[h*N_+t];
                const float* mc = &mcol[(h&1)*N_];
                float l0 = ledst, l1 = 0.f, l2 = 0.f, l3 = 0.f;
                #pragma unroll
                for (int k=0;k<UNR;++k){
                    int j = (jpk[k>>2] >> ((k&3)*8)) & 255;
                    float v = mc[j];
                    if      ((k&3)==0) l0 = fmaf(dw[k], v, l0);
                    else if ((k&3)==1) l1 = fmaf(dw[k], v, l1);
                    else if ((k&3)==2) l2 = fmaf(dw[k], v, l2);
                    else               l3 = fmaf(dw[k], v, l3);
                }
                for (int k=UNR;k<cnt0;++k)
                    l0 = fmaf(d0w_l[k*N_+t], mc[d0j_l[k*N_+t]], l0);
                float LEd = (l0+l1)+(l2+l3);
                float rE  = fmaf(STD_, ne, G_*(LEd - rowsum*E)) + C2_*sigf(C1_*M);
                float uE  = fmaf(K_, u, tanh500(rE));
                float En  = satf(fmaf(DT_, Ev, E));
                float Evn = satf(fmaf(KEv, Ev, fmaf(KEu, uE, -KEx*E)));
                M=Mn; Mv=Mvn; I=In; Iv=Ivn; E=En; Ev=Evn;
            }
            __syncthreads();
        }
        // ===== outer boundary =====
        if (isr){ hist[smod*HP_+t] = M; emi[t] = E - I; }
        if (isg){
            led_part[gslot*N_+grow] = acc;
            // stage u/ne slab for s+1 (one L2 drain per outer step)
            int sn = s+1; if (sn >= B_) sn = B_-1;
            #pragma unroll
            for (int r=0;r<5;++r){
                int p = r*NG_ + gt;
                int hh = p / N_, ii = p - hh*N_;
                uslab[hh*N_+ii]  = input[ii*(H_*B_) + hh*B_ + sn];
                neslab[hh*N_+ii] = noise_in[(ii*(H_*B_) + hh*B_ + sn)*3];
            }
        }
        __syncthreads();
        if (isr){
            float v = led_part[t]+led_part[N_+t]+led_part[2*N_+t]+led_part[3*N_+t];
            // d==1 term: col 1 during s+1 is M_end(s) = mcol buffer 0 (H even)
            #pragma unroll
            for (int k=0;k<UNR;++k)
                v = fmaf(d1w_l[k*N_+t], mcol[d1j_l[k*N_+t]], v);
            for (int k=UNR;k<cnt1;++k)
                v = fmaf(d1w_l[k*N_+t], mcol[d1j_l[k*N_+t]], v);
            ledst = v;
        }
        {   // eeg
            int o = t>>4, l = t&15;
            float il = frcp(lmrs[o]);
            float a2 = 0.f;
            for (int j=l;j<N_;j+=16)
                a2 = fmaf(fmaf(lm[o*N_+j], il, -colmean[j]), emi[j], a2);
            a2 += __shfl_down(a2,8,16); a2 += __shfl_down(a2,4,16);
            a2 += __shfl_down(a2,2,16); a2 += __shfl_down(a2,1,16);
            if (l==0) out[o*B_+s] = fmaf(CY0_, a2, -Y0_);
        }
        smod = ts;
        __syncthreads();
    }

    // final state
    if (isr){
        float* cs = out + OUT_*B_ + t*6;
        cs[0]=M; cs[1]=E; cs[2]=I; cs[3]=Mv; cs[4]=Ev; cs[5]=Iv;
    }
}

} // namespace

extern "C" void kernel_launch(void* const* d_in, const int* in_sizes, int n_in,
                              void* d_out, int out_size, void* d_ws, size_t ws_size,
                              hipStream_t stream)
{
    const float* input    = (const float*)d_in[0];
    const float* noise_in = (const float*)d_in[1];
    const float* hx   = (const float*)d_in[3];
    const float* hEin = (const float*)d_in[4];
    const float* wbb  = (const float*)d_in[5];
    const float* lm   = (const float*)d_in[6];
    const float* sc   = (const float*)d_in[7];
    const int*   dist = (const int*)d_in[8];
    float* out = (float*)d_out;

    hipLaunchKernelGGL(jansen_kernel, dim3(1), dim3(NT_), 0, stream,
                       input, noise_in, hx, hEin, wbb, lm, sc, dist, out);
}

// Round 4
// 7923.322 us; speedup vs baseline: 2.0820x; 1.3114x over previous
//
#include <hip/hip_runtime.h>
#include <math.h>

namespace {

constexpr int N_   = 200;   // nodes
constexpr int H_   = 20;    // inner steps
constexpr int B_   = 400;   // outer steps
constexpr int OUT_ = 64;    // eeg channels
constexpr int BUF_ = 500;   // hE buffer length
constexpr int NT_  = 1024;  // 16 waves, single persistent workgroup
constexpr int HD_  = 50;    // history depth (max delay 49)
constexpr int HP_  = 201;   // padded history stride
constexpr int GT0  = 224;   // first gather thread
constexpr int NG_  = 800;   // gather threads (4 per row)
constexpr int EPT  = 50;    // entries per gather thread
constexpr int CAP  = 16;    // CSR capacity (d==0 / d==1), Binom(200,.02) max ~13
constexpr int UNR  = 12;    // unrolled CSR entries (tail loop covers the rest)

constexpr float L2E = 1.4426950408889634f;
constexpr float LN2 = 0.6931471805599453f;

constexpr float DT_  = 0.0001f;
constexpr float G_   = 1000.01f;
constexpr float C1_  = 135.01f;
constexpr float C2_  = 108.01f;
constexpr float C3_  = 33.76f;
constexpr float C4_  = 33.76f;
constexpr float STD_ = 250.0f;
constexpr float K_   = 5.5f;
constexpr float CY0_ = 5.0f;
constexpr float Y0_  = 2.0f;

constexpr float RL2E = 0.56f * L2E;
constexpr float V0R  = 6.0f * RL2E;
constexpr float TU_  = 2.0f * L2E / 500.0f;
constexpr float TS_  = 2.0f * L2E / 1000.0f;

// ddXv = Xv + DT*(A*a*u - 2a*Xv - a^2*X)
constexpr float KMv = 0.9798f, KMu = 0.0328250f, KMx = 1.0201f;
constexpr float KEv = 0.9798f, KEu = 0.0328250f, KEx = 1.0201f;
constexpr float KIv = 0.9898f, KIu = 0.1122000f, KIx = 0.2601f;

__device__ __forceinline__ float fexp2(float x){ return __builtin_amdgcn_exp2f(x); }
__device__ __forceinline__ float flog2(float x){ return __builtin_amdgcn_logf(x); }
__device__ __forceinline__ float frcp (float x){ return __builtin_amdgcn_rcpf(x); }

__device__ __forceinline__ float sigf(float x){
    return 5.0f * frcp(1.0f + fexp2(fmaf(-RL2E, x, V0R)));
}
__device__ __forceinline__ float tanh500(float x){
    return 500.0f - 1000.0f * frcp(1.0f + fexp2(x * TU_));
}
__device__ __forceinline__ float satf(float x){
    return 1000.0f - 2000.0f * frcp(1.0f + fexp2(x * TS_));
}
__device__ __forceinline__ float wl_f(const float* __restrict__ wbb,
                                      const float* __restrict__ sc,
                                      int i, int j){
    float w0 = fexp2(wbb[i*N_+j]*L2E) * sc[i*N_+j];
    float w1 = fexp2(wbb[j*N_+i]*L2E) * sc[j*N_+i];
    return flog2(1.0f + 0.5f*(w0+w1)) * LN2;
}

// ---- 1 block of 1024 threads = 16 waves = exactly 4 waves/EU.
// Second launch_bounds arg = MIN WAVES PER EU: 4 -> VGPR cap 128 (not the
// default 8-waves/EU target of 64, which spilled the 63-reg gather tables
// to scratch and made every barrier drain scratch latency).
__global__ __launch_bounds__(NT_, 4) void jansen_kernel(
    const float* __restrict__ input,     // (N,H,B)
    const float* __restrict__ noise_in,  // (N,H,B,3)
    const float* __restrict__ hx,        // (N,6)
    const float* __restrict__ hEin,      // (N,500)
    const float* __restrict__ wbb,       // (N,N)
    const float* __restrict__ lm,        // (64,N)
    const float* __restrict__ sc,        // (N,N)
    const int*   __restrict__ dist,      // (N,N)
    float* __restrict__ out)             // 64*400 eeg + N*6 state
{
    __shared__ float hist[HD_*HP_];          // circular M_end history
    __shared__ float uslab[H_*N_];           // u for current outer step
    __shared__ float neslab[H_*N_];          // noise for current outer step
    __shared__ float d0w_l[CAP*N_];          // d==0 CSR weights (SoA)
    __shared__ unsigned char d0j_l[CAP*N_];  // d==0 CSR j (u8)
    __shared__ float d1w_l[CAP*N_];          // d==1 CSR weights
    __shared__ unsigned char d1j_l[CAP*N_];  // d==1 CSR j
    __shared__ float led_part[4*N_];         // static-gather partials
    __shared__ float mcol[2*N_];             // double-buffered hEb col 0
    __shared__ float emi[N_];
    __shared__ float colmean[N_];
    __shared__ float lmrs[OUT_];
    __shared__ float red_s[NT_/64];
    __shared__ float norm_s;

    const int t = threadIdx.x;
    const bool isr = (t < N_);
    const bool isg = (t >= GT0);             // 800 gather threads
    const int  gt  = t - GT0;                // 0..799
    const int  grow  = gt >> 2;              // row 0..199
    const int  gslot = gt & 3;               // slot 0..3
    const int  jbase = gslot * EPT;          // this thread's first j

    float wreg[EPT];                         // static weights (normalized)
    unsigned dpk[13];                        // delays, 4 x u8 per u32

    // ===== S0: lmrs + state/hist/mcol init + initial slab (b=0) =====
    if (t < OUT_){
        float s2 = 0.f;
        for (int j=0;j<N_;++j) s2 += fabsf(lm[t*N_+j]);
        lmrs[t] = s2;
    }
    float M=0,E=0,I=0,Mv=0,Ev=0,Iv=0, rowsum=0, ledst=0;
    int cnt0=0, cnt1=0;
    if (isr){
        for (int k=1;k<HD_;++k) hist[(HD_-k)*HP_+t] = hEin[t*BUF_+k];
        mcol[t] = hEin[t*BUF_];
        M=hx[t*6+0]; E=hx[t*6+1]; I=hx[t*6+2];
        Mv=hx[t*6+3]; Ev=hx[t*6+4]; Iv=hx[t*6+5];
    }
    if (isg){
        #pragma unroll
        for (int r=0;r<5;++r){
            int p = r*NG_ + gt;
            int hh = p / N_, ii = p - hh*N_;
            uslab[hh*N_+ii]  = input[ii*(H_*B_) + hh*B_];
            neslab[hh*N_+ii] = noise_in[(ii*(H_*B_) + hh*B_)*3];
        }
    }
    __syncthreads();

    // ===== S1: gather wl entries, Frobenius + rowsum partials =====
    float ss = 0.f, rs = 0.f;
    #pragma unroll
    for (int k=0;k<13;++k) dpk[k] = 0u;
    #pragma unroll
    for (int m=0;m<EPT;++m){
        float w = 0.f; int d = 2;
        int j = jbase + m;
        if (isg){
            d = dist[j*N_+grow] >> 1;        // delays[j][grow]
            w = wl_f(wbb, sc, grow, j);
        }
        ss = fmaf(w,w,ss); rs += w;
        wreg[m] = (d>=2) ? w : 0.f;
        int dm = (d<2) ? 2 : d;              // clamp: d<2 handled by CSRs
        dpk[m>>2] |= (unsigned)dm << ((m&3)*8);
    }
    if (isr){                                 // colmean (needs lmrs)
        float cm=0.f;
        for (int o=0;o<OUT_;++o) cm += lm[o*N_+t] * frcp(lmrs[o]);
        colmean[t] = cm * (1.0f/(float)OUT_);
    }
    #pragma unroll
    for (int o=32;o>0;o>>=1) ss += __shfl_down(ss,o,64);
    if ((t&63)==0) red_s[t>>6] = ss;
    __syncthreads();
    if (t==0){ float tot=0.f; for (int w=0;w<NT_/64;++w) tot+=red_s[w]; norm_s = sqrtf(tot); }
    __syncthreads();
    const float inv = 1.0f / norm_s;
    #pragma unroll
    for (int m=0;m<EPT;++m) wreg[m] *= inv;
    if (isg) led_part[gslot*N_+grow] = rs;    // raw rowsum partial

    // ===== S3: row CSR build (d<2), registers for d0 =====
    float dw[UNR]; unsigned jpk[3];
    #pragma unroll
    for (int k=0;k<UNR;++k) dw[k] = 0.f;
    jpk[0]=jpk[1]=jpk[2]=0u;
    if (isr){
        #pragma unroll
        for (int k=0;k<UNR;++k){ d0w_l[k*N_+t]=0.f; d0j_l[k*N_+t]=0;
                                 d1w_l[k*N_+t]=0.f; d1j_l[k*N_+t]=0; }
        for (int j=0;j<N_;++j){
            int dd = dist[j*N_+t] >> 1;
            if (dd < 2){
                float w = wl_f(wbb, sc, t, j) * inv;
                if (dd==0){ if (cnt0<CAP){ d0w_l[cnt0*N_+t]=w; d0j_l[cnt0*N_+t]=(unsigned char)j; ++cnt0; } }
                else      { if (cnt1<CAP){ d1w_l[cnt1*N_+t]=w; d1j_l[cnt1*N_+t]=(unsigned char)j; ++cnt1; } }
            }
        }
        #pragma unroll
        for (int k=0;k<UNR;++k){
            dw[k] = d0w_l[k*N_+t];
            unsigned jv = d0j_l[k*N_+t];
            jpk[k>>2] |= jv << ((k&3)*8);
        }
    }
    __syncthreads();

    // ===== S4: rowsum =====
    if (isr){
        rowsum = (led_part[t]+led_part[N_+t]+led_part[2*N_+t]+led_part[3*N_+t]) * inv;
    }
    __syncthreads();

    // ===== S5: initial static gather for s=0 (target step 0 -> c = 50-d) =====
    if (isg){
        float a0 = 0.f;
        #pragma unroll
        for (int m=0;m<EPT;++m){
            int d = (int)((dpk[m>>2] >> ((m&3)*8)) & 255u);
            int c = HD_ - d;                 // d in [2,49] -> c in [1,48]
            a0 = fmaf(wreg[m], hist[c*HP_ + jbase + m], a0);
        }
        led_part[gslot*N_+grow] = a0;
    }
    __syncthreads();

    // ===== S6: initial ledst (+ d==1 from hE col 1 = slot 49) =====
    if (isr){
        float v = led_part[t]+led_part[N_+t]+led_part[2*N_+t]+led_part[3*N_+t];
        #pragma unroll
        for (int k=0;k<UNR;++k)
            v = fmaf(d1w_l[k*N_+t], hist[49*HP_ + d1j_l[k*N_+t]], v);
        for (int k=UNR;k<cnt1;++k)
            v = fmaf(d1w_l[k*N_+t], hist[49*HP_ + d1j_l[k*N_+t]], v);
        ledst = v;
    }
    __syncthreads();

    // ===== main loop =====
    int smod = 0;
    for (int s=0; s<B_; ++s){
        int ts = smod+1; if (ts==HD_) ts = 0;      // (s+1) % 50
        float acc = 0.f;
        #pragma unroll
        for (int h=0; h<H_; ++h){
            // --- gather chunk for outer step s+1 (entries 5q+2r, 2 or 3) ---
            if (isg){
                const int eb = 5*(h>>1) + 2*(h&1);
                const int ec = (h&1) ? 3 : 2;
                #pragma unroll
                for (int k=0;k<3;++k){
                    if (k < ec){
                        const int m = eb + k;
                        int d = (int)((dpk[m>>2] >> ((m&3)*8)) & 255u);
                        int c = ts - d; if (c<0) c += HD_;
                        acc = fmaf(wreg[m], hist[c*HP_ + jbase + m], acc);
                    }
                }
            }
            if (isr){
                // --- M-path first: unblock next step ASAP ---
                float rM  = sigf(E - I);
                float uM  = tanh500(rM);
                float Mn  = satf(fmaf(DT_, Mv, M));
                float Mvn = satf(fmaf(KMv, Mv, fmaf(KMu, uM, -KMx*M)));
                mcol[((h&1)^1)*N_ + t] = Mn;
                // --- I-path (independent of LEd) ---
                float rI  = C4_*sigf(C3_*M);
                float uI  = tanh500(rI);
                float In  = satf(fmaf(DT_, Iv, I));
                float Ivn = satf(fmaf(KIv, Iv, fmaf(KIu, uI, -KIx*I)));
                // --- E-path ---
                float u  = uslab[h*N_+t];
                float ne = neslab[h*N_+t];
                const float* mc = &mcol[(h&1)*N_];
                float l0 = ledst, l1 = 0.f, l2 = 0.f, l3 = 0.f;
                #pragma unroll
                for (int k=0;k<UNR;++k){
                    int j = (jpk[k>>2] >> ((k&3)*8)) & 255;
                    float v = mc[j];
                    if      ((k&3)==0) l0 = fmaf(dw[k], v, l0);
                    else if ((k&3)==1) l1 = fmaf(dw[k], v, l1);
                    else if ((k&3)==2) l2 = fmaf(dw[k], v, l2);
                    else               l3 = fmaf(dw[k], v, l3);
                }
                for (int k=UNR;k<cnt0;++k)
                    l0 = fmaf(d0w_l[k*N_+t], mc[d0j_l[k*N_+t]], l0);
                float LEd = (l0+l1)+(l2+l3);
                float rE  = fmaf(STD_, ne, G_*(LEd - rowsum*E)) + C2_*sigf(C1_*M);
                float uE  = fmaf(K_, u, tanh500(rE));
                float En  = satf(fmaf(DT_, Ev, E));
                float Evn = satf(fmaf(KEv, Ev, fmaf(KEu, uE, -KEx*E)));
                M=Mn; Mv=Mvn; I=In; Iv=Ivn; E=En; Ev=Evn;
            }
            __syncthreads();
        }
        // ===== outer boundary =====
        if (isr){ hist[smod*HP_+t] = M; emi[t] = E - I; }
        if (isg){
            led_part[gslot*N_+grow] = acc;
            // stage u/ne slab for s+1 (one L2 drain per outer step)
            int sn = s+1; if (sn >= B_) sn = B_-1;
            #pragma unroll
            for (int r=0;r<5;++r){
                int p = r*NG_ + gt;
                int hh = p / N_, ii = p - hh*N_;
                uslab[hh*N_+ii]  = input[ii*(H_*B_) + hh*B_ + sn];
                neslab[hh*N_+ii] = noise_in[(ii*(H_*B_) + hh*B_ + sn)*3];
            }
        }
        __syncthreads();
        if (isr){
            float v = led_part[t]+led_part[N_+t]+led_part[2*N_+t]+led_part[3*N_+t];
            // d==1 term: col 1 during s+1 is M_end(s) = mcol buffer 0 (H even)
            #pragma unroll
            for (int k=0;k<UNR;++k)
                v = fmaf(d1w_l[k*N_+t], mcol[d1j_l[k*N_+t]], v);
            for (int k=UNR;k<cnt1;++k)
                v = fmaf(d1w_l[k*N_+t], mcol[d1j_l[k*N_+t]], v);
            ledst = v;
        }
        {   // eeg
            int o = t>>4, l = t&15;
            float il = frcp(lmrs[o]);
            float a2 = 0.f;
            for (int j=l;j<N_;j+=16)
                a2 = fmaf(fmaf(lm[o*N_+j], il, -colmean[j]), emi[j], a2);
            a2 += __shfl_down(a2,8,16); a2 += __shfl_down(a2,4,16);
            a2 += __shfl_down(a2,2,16); a2 += __shfl_down(a2,1,16);
            if (l==0) out[o*B_+s] = fmaf(CY0_, a2, -Y0_);
        }
        smod = ts;
        __syncthreads();
    }

    // final state
    if (isr){
        float* cs = out + OUT_*B_ + t*6;
        cs[0]=M; cs[1]=E; cs[2]=I; cs[3]=Mv; cs[4]=Ev; cs[5]=Iv;
    }
}

} // namespace

extern "C" void kernel_launch(void* const* d_in, const int* in_sizes, int n_in,
                              void* d_out, int out_size, void* d_ws, size_t ws_size,
                              hipStream_t stream)
{
    const float* input    = (const float*)d_in[0];
    const float* noise_in = (const float*)d_in[1];
    const float* hx   = (const float*)d_in[3];
    const float* hEin = (const float*)d_in[4];
    const float* wbb  = (const float*)d_in[5];
    const float* lm   = (const float*)d_in[6];
    const float* sc   = (const float*)d_in[7];
    const int*   dist = (const int*)d_in[8];
    float* out = (float*)d_out;

    hipLaunchKernelGGL(jansen_kernel, dim3(1), dim3(NT_), 0, stream,
                       input, noise_in, hx, hEin, wbb, lm, sc, dist, out);
}